// Round 10
// baseline (99.142 us; speedup 1.0000x reference)
//
#include <hip/hip_runtime.h>

// SecConv2d over Z_{2^32} via i8 MFMA, 4-chain biased-operand scheme (exact).
//   s(x) = x_byte - 128 per limb  => X = s(al) + 256*s(ah) + 32896
//   s(w) likewise                 => W = s0 + 256*s1 + 32896
//   out = P00 + (P01+P10)<<8 + P11<<16 + 32896*Q[p] + K[k]   (mod 2^32)
//   Q = 3x3 box sum of S[p], S[p] = sum_c (X_true - 32896) (border cells are
//   bytes 0x80 == s=-128 -> uniformly "interior with x=0", exact).
//
// R10: R9 structure (4 out rows x 56 cols/block, 448 blocks, one co-resident
// round) + micro-cuts on the per-wave critical path:
//   - weight frags/offsets loaded BEFORE staging (latency overlap)
//   - S stored pre-scaled by 32896; horizontal 3-sums ssr precomputed once
//     per block -> epilogue Q = 3 LDS reads + 2 adds (was 9 reads + mul)

typedef int v4i __attribute__((ext_vector_type(4)));

#define LCOL 144               // LDS col stride (128 B payload + 16 pad)
#define LROW (58 * LCOL)       // 8352 B per LDS halo row

__device__ __align__(16) unsigned char g_wb[2 * 9 * 64 * 64];
__device__ unsigned g_off[64];

static __device__ __forceinline__ unsigned bsum(unsigned v, unsigned acc) {
#if __has_builtin(__builtin_amdgcn_sad_u8)
    return __builtin_amdgcn_sad_u8(v, 0u, acc);
#else
    return acc + (v & 0xFFu) + ((v >> 8) & 0xFFu) + ((v >> 16) & 0xFFu) + (v >> 24);
#endif
}

__global__ __launch_bounds__(256) void packw(const int* __restrict__ w,
                                             const int* __restrict__ bias) {
    int blk = blockIdx.x;
    if (blk < 144) {
        int i = blk * 256 + threadIdx.x;        // [k][c][t] flat, 36864
        if (i >= 64 * 64 * 9) return;
        int k = i / 576;
        int r = i - k * 576;
        int c = r / 9;
        int t = r - c * 9;
        unsigned v = (unsigned)w[i];
        g_wb[((0 * 9 + t) * 64 + k) * 64 + c] = (unsigned char)((v & 255u) ^ 0x80u);
        g_wb[((1 * 9 + t) * 64 + k) * 64 + c] = (unsigned char)(((v >> 8) & 255u) ^ 0x80u);
    } else {
        int k    = threadIdx.x >> 2;            // 4 threads per k
        int part = threadIdx.x & 3;
        int s0 = 0, s1 = 0;
        for (int j = part * 144; j < part * 144 + 144; ++j) {
            unsigned W = (unsigned)w[k * 576 + j];
            s0 += (int)(W & 255u);
            s1 += (int)((W >> 8) & 255u);
        }
        s0 += __shfl_xor(s0, 1); s0 += __shfl_xor(s0, 2);
        s1 += __shfl_xor(s1, 1); s1 += __shfl_xor(s1, 2);
        if (part == 0) {
            s0 -= 73728;                        // -128*576
            s1 -= 73728;
            unsigned ws = (unsigned)(s0 + 256 * s1);
            g_off[k] = (unsigned)bias[k] + 32896u * ws + 1082146816u * 576u;
        }
    }
}

__global__ __launch_bounds__(256, 2) void secconv(const int* __restrict__ x,
                                                  int* __restrict__ out)
{
    __shared__ unsigned char sx[6 * LROW];      // 50112 B
    __shared__ unsigned ss[6 * 58];             // 32896*S per halo pixel
    __shared__ unsigned ssr[6 * 56];            // horizontal 3-sums of ss

    const int tid  = threadIdx.x;
    const int blk  = blockIdx.x;                // 448 = 8 xcd * 56
    const int q    = blk >> 3;
    const int rg   = q % 14;                    // row-group of 4 output rows
    const int n    = (blk & 7) + 8 * (q / 14);
    const int wid  = tid >> 6;
    const int lane = tid & 63;
    const int lm   = lane & 15;
    const int lq   = lane >> 4;
    const int kp   = wid & 1;                   // ktile-pair -> k base kp*32
    const int ph   = wid >> 1;                  // row-pair within the 4 rows
    const int kbase = kp * 32;

    // ---- weight fragments + offsets FIRST (latency overlaps pack VALU) ----
    v4i wf[2][2][9];
#pragma unroll
    for (int kt = 0; kt < 2; ++kt)
#pragma unroll
        for (int l = 0; l < 2; ++l)
#pragma unroll
            for (int t = 0; t < 9; ++t)
                wf[kt][l][t] = *(const v4i*)(g_wb +
                    ((l * 9 + t) * 64 + (kbase + kt * 16 + lm)) * 64 + lq * 16);
    unsigned offv[2][4];
#pragma unroll
    for (int kt = 0; kt < 2; ++kt)
#pragma unroll
        for (int r = 0; r < 4; ++r)
            offv[kt][r] = g_off[kbase + kt * 16 + lq * 4 + r];

    // ---- fused pack: 348 halo pixels; transpose 64 ch to bytes ----
    for (int it = tid; it < 348; it += 256) {
        const int pr = it / 58, pc = it - pr * 58;
        const int ih = 4 * rg - 1 + pr, iw = pc - 1;
        unsigned char* ob = sx + pr * LROW + pc * LCOL;
        unsigned S;
        if ((unsigned)ih < 56u && (unsigned)iw < 56u) {
            const int* xp = x + (long)n * 64 * 3136 + ih * 56 + iw;
            unsigned slo = 0, shi = 0;
#pragma unroll
            for (int g = 0; g < 4; ++g) {       // 4 groups of 16 channels
                unsigned lo[4], hi[4];
#pragma unroll
                for (int u = 0; u < 4; ++u) {
                    const int c = g * 16 + u * 4;
                    unsigned v0 = (unsigned)xp[(c + 0) * 3136];
                    unsigned v1 = (unsigned)xp[(c + 1) * 3136];
                    unsigned v2 = (unsigned)xp[(c + 2) * 3136];
                    unsigned v3 = (unsigned)xp[(c + 3) * 3136];
                    unsigned t01 = __builtin_amdgcn_perm(v1, v0, 0x05040100u);
                    unsigned t23 = __builtin_amdgcn_perm(v3, v2, 0x05040100u);
                    unsigned lw  = __builtin_amdgcn_perm(t23, t01, 0x06040200u);
                    unsigned hw  = __builtin_amdgcn_perm(t23, t01, 0x07050301u);
                    slo = bsum(lw, slo);
                    shi = bsum(hw, shi);
                    lo[u] = lw ^ 0x80808080u;
                    hi[u] = hw ^ 0x80808080u;
                }
                *(uint4*)(ob + g * 16)      = make_uint4(lo[0], lo[1], lo[2], lo[3]);
                *(uint4*)(ob + 64 + g * 16) = make_uint4(hi[0], hi[1], hi[2], hi[3]);
            }
            S = 32896u * ((slo + (shi << 8)) - 2105344u);   // -64*32896
        } else {
            uint4 v = make_uint4(0x80808080u, 0x80808080u, 0x80808080u, 0x80808080u);
#pragma unroll
            for (int g = 0; g < 4; ++g) {
                *(uint4*)(ob + g * 16)      = v;
                *(uint4*)(ob + 64 + g * 16) = v;
            }
            S = 32896u * (unsigned)(-2105344);
        }
        ss[it] = S;
    }

    __syncthreads();

    // ---- horizontal 3-sums of the scaled S plane ----
    for (int it = tid; it < 336; it += 256) {
        const int r = it / 56, c = it - r * 56;
        ssr[it] = ss[r * 58 + c] + ss[r * 58 + c + 1] + ss[r * 58 + c + 2];
    }

    __syncthreads();

    const int r8 = lm >> 3, c8 = lm & 7;        // pixel tile: 2 rows x 8 cols
    const int lrow = 2 * ph + r8;               // LDS halo row of this lane
    const unsigned char* lbase = sx + lrow * LROW + c8 * LCOL + lq * 16;

    for (int t = 0; t < 7; ++t) {               // 7 col-groups of 8
        const unsigned char* tb = lbase + t * 8 * LCOL;
        v4i a00[2] = {{0,0,0,0},{0,0,0,0}}, a01[2] = {{0,0,0,0},{0,0,0,0}};
        v4i a10[2] = {{0,0,0,0},{0,0,0,0}}, a11[2] = {{0,0,0,0},{0,0,0,0}};
#pragma unroll
        for (int tap = 0; tap < 9; ++tap) {
            const int dr = tap / 3, dc = tap - (tap / 3) * 3;
            const unsigned char* pp = tb + dr * LROW + dc * LCOL;
            v4i bl = *(const v4i*)(pp);
            v4i bh = *(const v4i*)(pp + 64);
#pragma unroll
            for (int kt = 0; kt < 2; ++kt) {
                a00[kt] = __builtin_amdgcn_mfma_i32_16x16x64_i8(wf[kt][0][tap], bl, a00[kt], 0, 0, 0);
                a01[kt] = __builtin_amdgcn_mfma_i32_16x16x64_i8(wf[kt][0][tap], bh, a01[kt], 0, 0, 0);
                a10[kt] = __builtin_amdgcn_mfma_i32_16x16x64_i8(wf[kt][1][tap], bl, a10[kt], 0, 0, 0);
                a11[kt] = __builtin_amdgcn_mfma_i32_16x16x64_i8(wf[kt][1][tap], bh, a11[kt], 0, 0, 0);
            }
        }

        const int pc = t * 8 + c8;
        const unsigned qq = ssr[lrow * 56 + pc]
                          + ssr[(lrow + 1) * 56 + pc]
                          + ssr[(lrow + 2) * 56 + pc];

        const long pix = (long)(4 * rg + lrow) * 56 + pc;
#pragma unroll
        for (int kt = 0; kt < 2; ++kt) {
            const long ob = ((long)n * 64 + kbase + kt * 16 + lq * 4) * 3136 + pix;
#pragma unroll
            for (int r = 0; r < 4; ++r) {
                unsigned val = (unsigned)a00[kt][r]
                             + (((unsigned)a01[kt][r] + (unsigned)a10[kt][r]) << 8)
                             + ((unsigned)a11[kt][r] << 16)
                             + qq + offv[kt][r];
                out[ob + (long)r * 3136] = (int)val;
            }
        }
    }
}

extern "C" void kernel_launch(void* const* d_in, const int* in_sizes, int n_in,
                              void* d_out, int out_size, void* d_ws, size_t ws_size,
                              hipStream_t stream)
{
    const int* x    = (const int*)d_in[0];
    const int* w    = (const int*)d_in[1];
    const int* bias = (const int*)d_in[2];
    int* out        = (int*)d_out;

    packw  <<<dim3(145), dim3(256), 0, stream>>>(w, bias);
    secconv<<<dim3(448), dim3(256), 0, stream>>>(x, out);
}